// Round 4
// baseline (299.523 us; speedup 1.0000x reference)
//
#include <hip/hip_runtime.h>

// PoseCost: SE(3) log-map pose error over N = B*H poses.
// in:  pos [N,3] f32, rot [N,9] f32 (row-major 3x3), goal_pos [3], goal_rot [9], vec_weight [6]
// out: cost [N], rot_err [N], pos_err [N], v [N,3], omega [N,3]  (concat flat, f32)
//
// R4 structure: persistent grid-stride waves + register double-buffered pipeline.
//  - 512 blocks x 256 thr -> 8 four-pose chunks/thread at N=4.19M (exact balance)
//  - chunk k+1's 12 dwordx4 loads issue BEFORE chunk k's compute -> loads always in
//    flight (counted vmcnt instead of one-shot vmcnt(0) per wave)
//  - all outputs packed aligned dwordx4 stores, fire-and-forget, overlap next loads
//  - zero LDS, zero barriers. Math identical to R3 (verified).

#define BLOCK 256
#define GRID_BLOCKS 512

typedef float f32x4 __attribute__((ext_vector_type(4)));

__device__ __forceinline__ void pose_one(
    const float* R, float p0, float p1, float p2,
    const float* G, float g0, float g1, float g2, const float* w,
    float& cost, float& re, float& pe,
    float& v0, float& v1, float& v2,
    float& o0, float& o1, float& o2)
{
    // d = goal_pos - p ;  t_ge = R^T d
    const float d0 = g0 - p0, d1 = g1 - p1, d2 = g2 - p2;
    const float tq0 = R[0] * d0 + R[3] * d1 + R[6] * d2;
    const float tq1 = R[1] * d0 + R[4] * d1 + R[7] * d2;
    const float tq2 = R[2] * d0 + R[5] * d1 + R[8] * d2;

    // M = R^T * G
    float M[9];
    #pragma unroll
    for (int i = 0; i < 3; ++i)
        #pragma unroll
        for (int j = 0; j < 3; ++j)
            M[i * 3 + j] = R[0 + i] * G[0 + j] + R[3 + i] * G[3 + j] + R[6 + i] * G[6 + j];

    const float tr = M[0] + M[4] + M[8];
    float cos_t = (tr - 1.0f) * 0.5f;
    cos_t = fminf(fmaxf(cos_t, -1.0f + 1e-7f), 1.0f - 1e-7f);
    const float theta = acosf(cos_t);
    // sin(acos(c)) == sqrt(1-c^2) on (0,pi); fmaf keeps the clamp-boundary value accurate
    const float sin_t = sqrtf(fmaf(-cos_t, cos_t, 1.0f));

    // vee(M - M^T)/2
    const float wv0 = 0.5f * (M[7] - M[5]);
    const float wv1 = 0.5f * (M[2] - M[6]);
    const float wv2 = 0.5f * (M[3] - M[1]);

    const bool small = theta < 1e-4f;   // dead after the clamp but preserves ref semantics
    const float th2 = theta * theta;
    const float scale = small ? (1.0f + th2 * (1.0f / 6.0f)) : (theta / sin_t);
    o0 = scale * wv0; o1 = scale * wv1; o2 = scale * wv2;

    // A = (1 - theta*sin/(2(1-cos)))/theta^2 == (1 - 0.5*scale*(1+cos))/theta^2
    const float A = small ? (1.0f / 12.0f)
                          : (1.0f - 0.5f * scale * (1.0f + cos_t)) / th2;

    // v = t - 0.5*(omega x t) + A*(omega*(omega.t) - |omega|^2 * t)
    const float cx0 = o1 * tq2 - o2 * tq1;
    const float cx1 = o2 * tq0 - o0 * tq2;
    const float cx2 = o0 * tq1 - o1 * tq0;
    const float odt = o0 * tq0 + o1 * tq1 + o2 * tq2;
    const float on2 = o0 * o0 + o1 * o1 + o2 * o2;
    v0 = tq0 - 0.5f * cx0 + A * (o0 * odt - on2 * tq0);
    v1 = tq1 - 0.5f * cx1 + A * (o1 * odt - on2 * tq1);
    v2 = tq2 - 0.5f * cx2 + A * (o2 * odt - on2 * tq2);

    const float we0 = w[0] * o0, we1 = w[1] * o1, we2 = w[2] * o2;
    const float wp0 = w[3] * v0, wp1 = w[4] * v1, wp2 = w[5] * v2;
    re = we0 * we0 + we1 * we1 + we2 * we2;
    pe = wp0 * wp0 + wp1 * wp1 + wp2 * wp2;
    re = (re < 0.0f) ? 0.0f : re;   // CONV_* = 0 exact semantics
    pe = (pe < 0.0f) ? 0.0f : pe;
    cost = 15.0f * re + 100.0f * pe;
}

__device__ __forceinline__ void load_chunk(
    f32x4 (&r)[9], f32x4 (&p)[3],
    const float* __restrict__ rot, const float* __restrict__ pos, size_t c)
{
    const f32x4* rs = reinterpret_cast<const f32x4*>(rot + c * 36);  // 144 B, 16B-aligned
    const f32x4* ps = reinterpret_cast<const f32x4*>(pos + c * 12);  // 48 B, 16B-aligned
    #pragma unroll
    for (int k = 0; k < 9; ++k) r[k] = rs[k];
    #pragma unroll
    for (int k = 0; k < 3; ++k) p[k] = ps[k];
}

__device__ __forceinline__ void process_chunk(
    const f32x4 (&r)[9], const f32x4 (&p)[3], size_t c, size_t Ns,
    const float (&G)[9], float g0, float g1, float g2, const float (&w)[6],
    float* __restrict__ out)
{
    f32x4 vcost, vre, vpe, vv[3], vo[3];

    #define RF(q) (r[(q) >> 2][(q) & 3])
    #define PF(q) (p[(q) >> 2][(q) & 3])
    #define VV(q) (vv[(q) >> 2][(q) & 3])
    #define VO(q) (vo[(q) >> 2][(q) & 3])

    #pragma unroll
    for (int j = 0; j < 4; ++j) {
        float R[9];
        #pragma unroll
        for (int k = 0; k < 9; ++k) R[k] = RF(9 * j + k);
        const float p0 = PF(3 * j + 0);
        const float p1 = PF(3 * j + 1);
        const float p2 = PF(3 * j + 2);

        float cst, re, pe, v0, v1, v2, o0, o1, o2;
        pose_one(R, p0, p1, p2, G, g0, g1, g2, w,
                 cst, re, pe, v0, v1, v2, o0, o1, o2);
        vcost[j] = cst; vre[j] = re; vpe[j] = pe;
        VV(3 * j + 0) = v0; VV(3 * j + 1) = v1; VV(3 * j + 2) = v2;
        VO(3 * j + 0) = o0; VO(3 * j + 1) = o1; VO(3 * j + 2) = o2;
    }
    #undef RF
    #undef PF
    #undef VV
    #undef VO

    // aligned packed stores (requires N % 4 == 0, guaranteed on this path)
    *reinterpret_cast<f32x4*>(out + 4 * c) = vcost;
    *reinterpret_cast<f32x4*>(out + Ns + 4 * c) = vre;
    *reinterpret_cast<f32x4*>(out + 2 * Ns + 4 * c) = vpe;
    f32x4* vd = reinterpret_cast<f32x4*>(out + 3 * Ns + 12 * c);
    f32x4* od = reinterpret_cast<f32x4*>(out + 6 * Ns + 12 * c);
    #pragma unroll
    for (int k = 0; k < 3; ++k) vd[k] = vv[k];
    #pragma unroll
    for (int k = 0; k < 3; ++k) od[k] = vo[k];
}

__global__ __launch_bounds__(BLOCK) void pose_cost_kernel(
    const float* __restrict__ pos,
    const float* __restrict__ rot,
    const float* __restrict__ gpos,
    const float* __restrict__ grot,
    const float* __restrict__ wvec,
    float* __restrict__ out,
    int N)
{
    const size_t nthr = (size_t)gridDim.x * BLOCK;
    const size_t tid = (size_t)blockIdx.x * BLOCK + threadIdx.x;
    const size_t Ns = (size_t)N;

    // uniform (wave-invariant) goal / weight data -> scalar (s_load) reads
    float G[9], w[6];
    #pragma unroll
    for (int k = 0; k < 9; ++k) G[k] = grot[k];
    const float g0 = gpos[0], g1 = gpos[1], g2 = gpos[2];
    #pragma unroll
    for (int k = 0; k < 6; ++k) w[k] = wvec[k];

    if ((N & 3) == 0) {
        // ---- pipelined persistent path: double-buffered 4-pose chunks ----
        const size_t CH = Ns / 4;
        f32x4 rA[9], pA[3], rB[9], pB[3];

        size_t cA = tid;
        if (cA < CH) {
            load_chunk(rA, pA, rot, pos, cA);
            for (;;) {
                const size_t cB = cA + nthr;
                const bool hasB = cB < CH;
                if (hasB) load_chunk(rB, pB, rot, pos, cB);     // prefetch next
                process_chunk(rA, pA, cA, Ns, G, g0, g1, g2, w, out);
                if (!hasB) break;
                const size_t cN = cB + nthr;
                const bool hasA = cN < CH;
                if (hasA) load_chunk(rA, pA, rot, pos, cN);     // prefetch next-next
                process_chunk(rB, pB, cB, Ns, G, g0, g1, g2, w, out);
                if (!hasA) break;
                cA = cN;
            }
        }
    } else {
        // ---- generic scalar grid-stride fallback (N not divisible by 4) ----
        for (size_t i = tid; i < Ns; i += nthr) {
            float R[9];
            #pragma unroll
            for (int k = 0; k < 9; ++k) R[k] = rot[i * 9 + k];
            const float p0 = pos[i * 3 + 0];
            const float p1 = pos[i * 3 + 1];
            const float p2 = pos[i * 3 + 2];

            float cst, re, pe, v0, v1, v2, o0, o1, o2;
            pose_one(R, p0, p1, p2, G, g0, g1, g2, w,
                     cst, re, pe, v0, v1, v2, o0, o1, o2);

            out[i] = cst;
            out[Ns + i] = re;
            out[2 * Ns + i] = pe;
            out[3 * Ns + i * 3 + 0] = v0;
            out[3 * Ns + i * 3 + 1] = v1;
            out[3 * Ns + i * 3 + 2] = v2;
            out[6 * Ns + i * 3 + 0] = o0;
            out[6 * Ns + i * 3 + 1] = o1;
            out[6 * Ns + i * 3 + 2] = o2;
        }
    }
}

extern "C" void kernel_launch(void* const* d_in, const int* in_sizes, int n_in,
                              void* d_out, int out_size, void* d_ws, size_t ws_size,
                              hipStream_t stream) {
    const float* pos  = (const float*)d_in[0];   // [N,3]
    const float* rot  = (const float*)d_in[1];   // [N,9]
    const float* gpos = (const float*)d_in[2];   // [3]
    const float* grot = (const float*)d_in[3];   // [9]
    const float* wv   = (const float*)d_in[4];   // [6]
    float* out = (float*)d_out;

    const int N = in_sizes[0] / 3;
    // persistent-ish grid: 512 blocks -> exactly 8 chunks/thread at N = 2048*2048
    int blocks = GRID_BLOCKS;
    const int maxNeeded = (int)(((size_t)N + 4 * BLOCK - 1) / (4 * BLOCK));
    if (blocks > maxNeeded) blocks = maxNeeded > 0 ? maxNeeded : 1;
    hipLaunchKernelGGL(pose_cost_kernel, dim3(blocks), dim3(BLOCK), 0, stream,
                       pos, rot, gpos, grot, wv, out, N);
}